// Round 6
// baseline (492.139 us; speedup 1.0000x reference)
//
#include <hip/hip_runtime.h>
#include <math.h>

// ---------- types / helpers ----------
typedef __attribute__((ext_vector_type(8))) short short8;   // 8 bf16 (4 VGPRs)
typedef __attribute__((ext_vector_type(4))) float f32x4;    // MFMA acc

#define MFMA16(a, b, c) __builtin_amdgcn_mfma_f32_16x16x32_bf16((a), (b), (c), 0, 0, 0)

__device__ inline unsigned int pack2(float lo, float hi) {
  unsigned int ulo = __float_as_uint(lo), uhi = __float_as_uint(hi);
  return (uhi & 0xFFFF0000u) | (ulo >> 16);
}
__device__ inline unsigned short f2bf_r(float f) {
  return (unsigned short)((__float_as_uint(f) + 0x8000u) >> 16);
}
__device__ inline float bf2f(unsigned short h) {
  return __uint_as_float(((unsigned int)h) << 16);
}

// ---------- K0: merged weight repack ----------
// blocks 0..95:   W1 [3,2048,128] f32 -> W1bt [384,2048] bf16 (B^T, k-contiguous)
// blocks 96..287: W2 [3,128,128] f32  -> W2t  [j][d][c]  bf16 (transposed)
__global__ __launch_bounds__(256) void k_repack(const float* __restrict__ W1,
                                                const float* __restrict__ W2,
                                                unsigned short* __restrict__ W1bt,
                                                unsigned short* __restrict__ W2t) {
  __shared__ float tile[64 * 128];   // 32 KB
  const int b = blockIdx.x, tid = threadIdx.x;
  if (b < 96) {
    const int k = b >> 5, et = b & 31;
    const int e0 = et * 64;
    const float* src = W1 + (size_t)k * 262144 + (size_t)e0 * 128;
#pragma unroll
    for (int i = 0; i < 8; ++i) {
      int idx4 = tid + i * 256;
      ((f32x4*)tile)[idx4] = ((const f32x4*)src)[idx4];
    }
    __syncthreads();
#pragma unroll
    for (int i = 0; i < 4; ++i) {
      int item = tid + i * 256;
      int c = item >> 3, eo = (item & 7) * 8;
      union { unsigned short h[8]; uint4 v; } t;
#pragma unroll
      for (int u = 0; u < 8; ++u) t.h[u] = f2bf_r(tile[(eo + u) * 128 + c]);
      *(uint4*)(W1bt + (size_t)(k * 128 + c) * 2048 + e0 + eo) = t.v;
    }
  } else {
    int idx = (b - 96) * 256 + tid;                 // 49152
    int j = idx >> 14, r = idx & 16383, d = r >> 7, c = r & 127;
    W2t[idx] = f2bf_r(W2[(size_t)j * 16384 + (size_t)c * 128 + d]);
  }
}

// ---------- K1: fused stage1 GEMM + tap-sum/tanh + stage2 GEMM + log-softmax ----------
// 512 blocks x 512 threads (8 waves), 64 out rows, 2 blocks/CU (16 waves/CU).
// NEW dataflow (r0-r5 all bottlenecked on the gl_lds-barrier structure):
//  * B-frags: LDS bypassed entirely. Each wave owns 48 cols; loads its 6 frags/chunk
//    straight global->VGPR (W1bt is L2-hot, 1.57 MB), issued ONE CHUNK AHEAD.
//  * A: thread-level global->reg (prefetch 2 ahead) -> f32->bf16 convert ONCE
//    (was duplicated 8x across waves) -> swizzled bf16 LDS, double-buffered
//    (2 x 8704 B). A-frag = single ds_read_b128 (was 2 f32 reads + 4 pack2).
//  * One raw s_barrier + own lgkmcnt(0) per chunk. NO vmcnt drain in the loop:
//    all VMEM is consumed a full chunk after issue (compiler counts vmcnt).
// LDS per block 63744 B (A-bufs alias the Yt phase buffer).
__global__ __launch_bounds__(512, 4) void k_fused(const float* __restrict__ X,
                                                  const unsigned short* __restrict__ Bt,
                                                  const unsigned short* __restrict__ W2t,
                                                  const float* __restrict__ b1,
                                                  const float* __restrict__ b2,
                                                  float* __restrict__ out) {
  __shared__ __align__(16) char smem[63744];
  unsigned short* Yt = (unsigned short*)smem;             // phase B: 80 x 392 bf16 (62,720 B)
  float* zbuf = (float*)(smem + 62720);                   // 2 x 128 f32

  const int r0 = blockIdx.x * 64;
  const int tid = threadIdx.x, wave = tid >> 6, lane = tid & 63;
  const int mrow = lane & 15, quad = lane >> 4;

  // ---- A staging map: 68 rows x 16 f32x4-units = 1088 units/chunk.
  // thread t: units {t, t+512}; wave 7 threads also unit 1024+(t-448) (rows 64..67).
  // LDS bf16 row i (0..67) <-> X row r0-4+i; 128 B/row; 16B slot s at s^(i&7).
  const float *ap0, *ap1, *ap2;
  int lw0, lw1, lw2;
  {
    int u, r_, o_, g;
    u = tid;           r_ = u >> 4; o_ = u & 15;
    g = r0 - 4 + r_; if (g < 0) g = 0;
    ap0 = X + (size_t)g * 2048 + o_ * 4;
    lw0 = r_ * 128 + (((o_ >> 1) ^ (r_ & 7)) << 4) + ((o_ & 1) << 3);
    u = tid + 512;     r_ = u >> 4; o_ = u & 15;
    g = r0 - 4 + r_; if (g < 0) g = 0;
    ap1 = X + (size_t)g * 2048 + o_ * 4;
    lw1 = r_ * 128 + (((o_ >> 1) ^ (r_ & 7)) << 4) + ((o_ & 1) << 3);
    u = 1024 + (tid - 448); if (u < 1024) u = 1024;   // only wave 7 issues this
    r_ = u >> 4; o_ = u & 15;
    g = r0 - 4 + r_;
    ap2 = X + (size_t)g * 2048 + o_ * 4;
    lw2 = r_ * 128 + (((o_ >> 1) ^ (r_ & 7)) << 4) + ((o_ & 1) << 3);
  }
  f32x4 ar0, ar1, ar2;

  // ---- B-frag pointers: wave cols wave*48 + ct*16 + mrow; frag = 16B at k0+s*32+quad*8
  const unsigned short* bp0 = Bt + (size_t)(wave * 48 +  0 + mrow) * 2048 + quad * 8;
  const unsigned short* bp1 = Bt + (size_t)(wave * 48 + 16 + mrow) * 2048 + quad * 8;
  const unsigned short* bp2 = Bt + (size_t)(wave * 48 + 32 + mrow) * 2048 + quad * 8;
  short8 bfr[3][2];                                   // static-indexed only (rule #20)

  f32x4 acc[5][3] = {};   // 80 logical rows (5 rt; rows 68+ garbage, unused) x 48 cols

  auto loadA = [&]() {
    ar0 = *(const f32x4*)ap0; ap0 += 64;
    ar1 = *(const f32x4*)ap1; ap1 += 64;
    if (wave == 7) { ar2 = *(const f32x4*)ap2; ap2 += 64; }
  };
  auto convA = [&](char* buf) {
    uint2 v;
    v.x = pack2(ar0[0], ar0[1]); v.y = pack2(ar0[2], ar0[3]);
    *(uint2*)(buf + lw0) = v;
    v.x = pack2(ar1[0], ar1[1]); v.y = pack2(ar1[2], ar1[3]);
    *(uint2*)(buf + lw1) = v;
    if (wave == 7) {
      v.x = pack2(ar2[0], ar2[1]); v.y = pack2(ar2[2], ar2[3]);
      *(uint2*)(buf + lw2) = v;
    }
  };
  auto loadB = [&]() {
    bfr[0][0] = *(const short8*)(bp0); bfr[0][1] = *(const short8*)(bp0 + 32);
    bfr[1][0] = *(const short8*)(bp1); bfr[1][1] = *(const short8*)(bp1 + 32);
    bfr[2][0] = *(const short8*)(bp2); bfr[2][1] = *(const short8*)(bp2 + 32);
    bp0 += 64; bp1 += 64; bp2 += 64;
  };
  auto compute = [&](const char* buf) {
#pragma unroll
    for (int s = 0; s < 2; ++s) {
      const int swz = (((s * 4 + quad) ^ (mrow & 7)) << 4);
      short8 af[5];
#pragma unroll
      for (int rt = 0; rt < 5; ++rt)
        af[rt] = *(const short8*)(buf + (rt * 16 + mrow) * 128 + swz);
#pragma unroll
      for (int rt = 0; rt < 5; ++rt) {
        acc[rt][0] = MFMA16(af[rt], bfr[0][s], acc[rt][0]);
        acc[rt][1] = MFMA16(af[rt], bfr[1][s], acc[rt][1]);
        acc[rt][2] = MFMA16(af[rt], bfr[2][s], acc[rt][2]);
      }
    }
  };

  // ---- prologue: A(0)->LDS buf0; B(0)->regs; A(1)->regs ----
  loadA();                         // A(0)
  convA(smem);                     // auto vmcnt wait on A(0)
  loadB();                         // B(0), lands under first compute's frag reads
  loadA();                         // A(1)
  asm volatile("s_waitcnt lgkmcnt(0)" ::: "memory");
  __builtin_amdgcn_s_barrier();
  __builtin_amdgcn_sched_barrier(0);

#pragma unroll 2
  for (int t = 0; t < 32; ++t) {
    compute(smem + (t & 1) * 8704);          // uses B(t) regs + A-LDS[t&1]
    if (t < 31) {
      convA(smem + ((t + 1) & 1) * 8704);    // A(t+1) regs -> other buf (auto vmcnt)
      loadB();                               // B(t+1), in flight across next compute
      if (t < 30) loadA();                   // A(t+2)
      asm volatile("s_waitcnt lgkmcnt(0)" ::: "memory");
      __builtin_amdgcn_s_barrier();          // cross-wave: writes visible, reads done
      __builtin_amdgcn_sched_barrier(0);
    }
  }
  __syncthreads();                           // A-bufs die; Yt phase begins

  // ---- spill acc -> Yt (bf16). Yt row i <-> Y global row r0-4+i; stride 392 (4-bank shift) ----
#pragma unroll
  for (int rt = 0; rt < 5; ++rt)
#pragma unroll
    for (int ct = 0; ct < 3; ++ct)
#pragma unroll
      for (int rg = 0; rg < 4; ++rg) {
        int l = rt * 16 + quad * 4 + rg;
        int col = wave * 48 + ct * 16 + mrow;
        Yt[l * 392 + col] = f2bf_r(acc[rt][ct][rg]);
      }
  __syncthreads();

  // ---- H[p]=tanh(sum taps + cnt*b1), p in [r0-2, r0+63]; store in-place at dead tap-2 slot ----
  // H[p] slot = Yt[p-r0+2][256+c]. Self-RMW per element: race-free (blk0/blk1 never written).
  for (int idx = tid; idx < 66 * 128; idx += 512) {
    int hl = idx >> 7, c = idx & 127;
    int p = r0 - 2 + hl;
    int i = hl + 2;                                   // tap-0 Yt row
    float h = 0.f;
    if (p >= 0) {
      float s = bf2f(Yt[i * 392 + c]);
      float cnt = 1.f;
      if (p >= 1) { s += bf2f(Yt[(i - 1) * 392 + 128 + c]); cnt += 1.f; }
      if (p >= 2) { s += bf2f(Yt[(i - 2) * 392 + 256 + c]); cnt += 1.f; }
      h = tanhf(fmaf(cnt, b1[c], s));
    }
    Yt[(i - 2) * 392 + 256 + c] = f2bf_r(h);          // = Yt[hl][256+c], holds H[r0-2+hl]
  }
  __syncthreads();

  // ---- stage-2 (waves 0-3): Z rows r0+wave*16..+15; A-frag H row = Yt[wave*16+mrow+j][256+..] ----
  if (wave < 4) {
    f32x4 acc2[8] = {};
#pragma unroll
    for (int j = 0; j < 3; ++j) {
#pragma unroll
      for (int kk = 0; kk < 4; ++kk) {
        short8 a0 = *(const short8*)&Yt[(wave * 16 + mrow + j) * 392 + 256 + kk * 32 + quad * 8];
        const unsigned short* wp = W2t + (size_t)(j * 128 + mrow) * 128 + kk * 32 + quad * 8;
#pragma unroll
        for (int ct = 0; ct < 8; ++ct)
          acc2[ct] = MFMA16(a0, *(const short8*)(wp + ct * 16 * 128), acc2[ct]);
      }
    }

    // ---- log-softmax per row (128 cols = 16 lanes x 8 ct-regs) ----
#pragma unroll
    for (int rg = 0; rg < 4; ++rg) {
      float z[8]; float m = -1e30f;
#pragma unroll
      for (int ct = 0; ct < 8; ++ct) {
        z[ct] = acc2[ct][rg] + 3.f * b2[ct * 16 + mrow];
        m = fmaxf(m, z[ct]);
      }
#pragma unroll
      for (int off = 1; off < 16; off <<= 1) m = fmaxf(m, __shfl_xor(m, off, 64));
      float s = 0.f;
#pragma unroll
      for (int ct = 0; ct < 8; ++ct) s += __expf(z[ct] - m);
#pragma unroll
      for (int off = 1; off < 16; off <<= 1) s += __shfl_xor(s, off, 64);
      float lse = m + __logf(s);
      int grow = r0 + wave * 16 + quad * 4 + rg;
      if (grow >= 2) {
        float* op = out + (size_t)grow * 128 + mrow;
#pragma unroll
        for (int ct = 0; ct < 8; ++ct) op[ct * 16] = z[ct] - lse;
      }
    }
  }

  // ---- fallback rows 0,1 (block 0): Z0 = tanh(Y[row][0:128]+b1) @ W2[0] + b2 ----
  if (blockIdx.x == 0) {
    __syncthreads();
    int row = tid >> 7, d = tid & 127;
    if (tid < 256)
      zbuf[row * 128 + d] = tanhf(bf2f(Yt[(row + 4) * 392 + d]) + b1[d]);  // blk0 cols intact
    __syncthreads();
    float zv = 0.f;
    if (tid < 256) {
      zv = b2[d];
      for (int c = 0; c < 128; ++c)
        zv = fmaf(zbuf[row * 128 + c], bf2f(W2t[(size_t)d * 128 + c]), zv); // W2t[0][d][c]=W2[0][c][d]
    }
    __syncthreads();
    if (tid < 256) zbuf[row * 128 + d] = zv;
    __syncthreads();
    if (tid < 256) {
      float m = -1e30f;
      for (int c = 0; c < 128; ++c) m = fmaxf(m, zbuf[row * 128 + c]);
      float s = 0.f;
      for (int c = 0; c < 128; ++c) s += __expf(zbuf[row * 128 + c] - m);
      out[(size_t)row * 128 + d] = zv - m - __logf(s);
    }
  }
}

// ---------- launch ----------
extern "C" void kernel_launch(void* const* d_in, const int* in_sizes, int n_in,
                              void* d_out, int out_size, void* d_ws, size_t ws_size,
                              hipStream_t stream) {
  const float* X  = (const float*)d_in[0];   // [32768, 1, 2048]
  const float* W1 = (const float*)d_in[1];   // [3, 2048, 128]
  const float* b1 = (const float*)d_in[2];   // [1, 128]
  const float* W2 = (const float*)d_in[3];   // [3, 128, 128]
  const float* b2 = (const float*)d_in[4];   // [1, 128]
  float* out = (float*)d_out;                // [32768, 1, 128] fp32

  unsigned short* W1bt = (unsigned short*)d_ws;                    // 384*2048*2 = 1,572,864
  unsigned short* W2t  = (unsigned short*)((char*)d_ws + 1572864); // 98,304

  k_repack<<<288, 256, 0, stream>>>(W1, W2, W1bt, W2t);
  k_fused<<<512, 512, 0, stream>>>(X, W1bt, W2t, b1, b2, out);
}

// Round 7
// 419.798 us; speedup vs baseline: 1.1723x; 1.1723x over previous
//
#include <hip/hip_runtime.h>
#include <math.h>

// ---------- types / helpers ----------
typedef __attribute__((ext_vector_type(8))) short short8;   // 8 bf16 (4 VGPRs)
typedef __attribute__((ext_vector_type(4))) float f32x4;    // MFMA acc

#define MFMA16(a, b, c) __builtin_amdgcn_mfma_f32_16x16x32_bf16((a), (b), (c), 0, 0, 0)

// async global->LDS, 16B per lane (B staging only; coalesced, L2-temporal).
__device__ inline void gl_lds16(const void* g, void* l) {
  __builtin_amdgcn_global_load_lds(
      (const __attribute__((address_space(1))) void*)g,
      (__attribute__((address_space(3))) void*)l, 16, 0, 0);
}

__device__ inline unsigned int pack2(float lo, float hi) {
  unsigned int ulo = __float_as_uint(lo), uhi = __float_as_uint(hi);
  return (uhi & 0xFFFF0000u) | (ulo >> 16);
}
__device__ inline unsigned short f2bf_r(float f) {
  return (unsigned short)((__float_as_uint(f) + 0x8000u) >> 16);
}
__device__ inline float bf2f(unsigned short h) {
  return __uint_as_float(((unsigned int)h) << 16);
}

// ---------- K0: merged weight repack ----------
// blocks 0..95:   W1 [3,2048,128] f32 -> W1bt [384,2048] bf16 (B^T, k-contiguous)
// blocks 96..287: W2 [3,128,128] f32  -> W2t  [j][d][c]  bf16 (transposed)
__global__ __launch_bounds__(256) void k_repack(const float* __restrict__ W1,
                                                const float* __restrict__ W2,
                                                unsigned short* __restrict__ W1bt,
                                                unsigned short* __restrict__ W2t) {
  __shared__ float tile[64 * 128];   // 32 KB
  const int b = blockIdx.x, tid = threadIdx.x;
  if (b < 96) {
    const int k = b >> 5, et = b & 31;
    const int e0 = et * 64;
    const float* src = W1 + (size_t)k * 262144 + (size_t)e0 * 128;
#pragma unroll
    for (int i = 0; i < 8; ++i) {
      int idx4 = tid + i * 256;
      ((f32x4*)tile)[idx4] = ((const f32x4*)src)[idx4];
    }
    __syncthreads();
#pragma unroll
    for (int i = 0; i < 4; ++i) {
      int item = tid + i * 256;
      int c = item >> 3, eo = (item & 7) * 8;
      union { unsigned short h[8]; uint4 v; } t;
#pragma unroll
      for (int u = 0; u < 8; ++u) t.h[u] = f2bf_r(tile[(eo + u) * 128 + c]);
      *(uint4*)(W1bt + (size_t)(k * 128 + c) * 2048 + e0 + eo) = t.v;
    }
  } else {
    int idx = (b - 96) * 256 + tid;                 // 49152
    int j = idx >> 14, r = idx & 16383, d = r >> 7, c = r & 127;
    W2t[idx] = f2bf_r(W2[(size_t)j * 16384 + (size_t)c * 128 + d]);
  }
}

// ---------- K1: fused stage1 GEMM + tap-sum/tanh + stage2 GEMM + log-softmax ----------
// 512 blocks x 256 thr (4 waves), 64 out rows, 2 blocks/CU. Bottleneck identified r0-r6:
// ALL staged bytes (X 268MB + B re-staged 805MB) ride the ~6.33 TB/s L3/HBM fabric
// because the X stream evicts the 1.57MB W1bt panel from each XCD's L2.
// Fix: X loads are NONTEMPORAL (reg path, NT CPol) so L2 retains B; B staging keeps
// r0's coalesced gl_lds path. A: regs -> bf16 convert once -> swizzled LDS dbuf
// (2 x 8704 B); raw s_barrier + counted vmcnt(6) leaves next-next A chunk in flight.
__global__ __launch_bounds__(256, 2) void k_fused(const float* __restrict__ X,
                                                  const unsigned short* __restrict__ Bt,
                                                  const unsigned short* __restrict__ W2t,
                                                  const float* __restrict__ b1,
                                                  const float* __restrict__ b2,
                                                  float* __restrict__ out) {
  // smem: bufA0 [0,8704) bufA1 [8704,17408)  (68 rows x 128B bf16, slot j at j^(row&7))
  //       Blds  [17408,66560)                (384 cols x 128B, chunk c at c^(col&7))
  __shared__ __align__(16) char smem[66560];
  unsigned short* Blds = (unsigned short*)(smem + 17408);
  unsigned short* Yt = (unsigned short*)smem;             // phase B: 80 x 392 bf16 (62,720 B)
  float* zbuf = (float*)(smem + 62720);                   // 2 x 128 f32

  const int r0 = blockIdx.x * 64;
  const int tid = threadIdx.x, wave = tid >> 6, lane = tid & 63;
  const int mrow = lane & 15, quad = lane >> 4;

  // ---- A map: 68 rows x 8 slots = 544 pairs (pair = 8 floats = 16B bf16 slot).
  // wave w owns pairs w*136 + {lane, lane+64, lane+128 if lane<8} -> 6 loads/wave/chunk.
  const float *ap0, *ap1, *ap2;
  int lw0, lw1, lw2;
  {
    int p, r_, j, g;
    p = wave * 136 + lane;        r_ = p >> 3; j = p & 7;
    g = r0 - 4 + r_; if (g < 0) g = 0;
    ap0 = X + (size_t)g * 2048 + j * 8;
    lw0 = r_ * 128 + ((j ^ (r_ & 7)) << 4);
    p += 64;                      r_ = p >> 3; j = p & 7;
    g = r0 - 4 + r_; if (g < 0) g = 0;
    ap1 = X + (size_t)g * 2048 + j * 8;
    lw1 = r_ * 128 + ((j ^ (r_ & 7)) << 4);
    p += 64;                      r_ = p >> 3; j = p & 7;   // lane<8 only
    g = r0 - 4 + r_; if (g < 0) g = 0;
    ap2 = X + (size_t)g * 2048 + j * 8;
    lw2 = r_ * 128 + ((j ^ (r_ & 7)) << 4);
  }
  f32x4 a0a, a0b, a1a, a1b, a2a, a2b;

  // ---- B staging (r0 verbatim): 48 loads of 8 cols; wave w owns loads w*12..+11.
  const unsigned short* bgp[12];
#pragma unroll
  for (int r = 0; r < 12; ++r) {
    int col = wave * 96 + r * 8 + (lane >> 3);
    int c = (lane & 7) ^ (col & 7);
    bgp[r] = Bt + (size_t)col * 2048 + c * 8;
  }

  f32x4 acc[5][6] = {};   // 80 logical rows (5 rt; 68+ garbage unused) x 96 cols (6 ct)

  auto loadA = [&]() {     // nontemporal: keep X out of L2 so B stays resident
    a0a = __builtin_nontemporal_load((const f32x4*)ap0);
    a0b = __builtin_nontemporal_load((const f32x4*)(ap0 + 4));
    a1a = __builtin_nontemporal_load((const f32x4*)ap1);
    a1b = __builtin_nontemporal_load((const f32x4*)(ap1 + 4));
    if (lane < 8) {
      a2a = __builtin_nontemporal_load((const f32x4*)ap2);
      a2b = __builtin_nontemporal_load((const f32x4*)(ap2 + 4));
    }
    ap0 += 64; ap1 += 64; ap2 += 64;
  };
  auto convA = [&](char* buf) {
    union { unsigned int u[4]; uint4 v; } t;
    t.u[0] = pack2(a0a[0], a0a[1]); t.u[1] = pack2(a0a[2], a0a[3]);
    t.u[2] = pack2(a0b[0], a0b[1]); t.u[3] = pack2(a0b[2], a0b[3]);
    *(uint4*)(buf + lw0) = t.v;
    t.u[0] = pack2(a1a[0], a1a[1]); t.u[1] = pack2(a1a[2], a1a[3]);
    t.u[2] = pack2(a1b[0], a1b[1]); t.u[3] = pack2(a1b[2], a1b[3]);
    *(uint4*)(buf + lw1) = t.v;
    if (lane < 8) {
      t.u[0] = pack2(a2a[0], a2a[1]); t.u[1] = pack2(a2a[2], a2a[3]);
      t.u[2] = pack2(a2b[0], a2b[1]); t.u[3] = pack2(a2b[2], a2b[3]);
      *(uint4*)(buf + lw2) = t.v;
    }
  };
  auto stageB = [&]() {
#pragma unroll
    for (int r = 0; r < 12; ++r)
      gl_lds16(bgp[r], (char*)Blds + (wave * 96 + r * 8) * 128);
#pragma unroll
    for (int r = 0; r < 12; ++r) bgp[r] += 64;
  };
  auto compute = [&](const char* buf) {
#pragma unroll
    for (int s = 0; s < 2; ++s) {
      const int swz = ((s * 4 + quad) ^ (mrow & 7));
      short8 af[5];
#pragma unroll
      for (int rt = 0; rt < 5; ++rt)
        af[rt] = *(const short8*)(buf + (rt * 16 + mrow) * 128 + (swz << 4));
#pragma unroll
      for (int ct = 0; ct < 6; ++ct) {
        int col = wave * 96 + ct * 16 + mrow;
        short8 bf = *(const short8*)(Blds + col * 64 + swz * 8);
#pragma unroll
        for (int rt = 0; rt < 5; ++rt)
          acc[rt][ct] = MFMA16(af[rt], bf, acc[rt][ct]);
      }
    }
  };

  // ---- prologue: A(0)->regs->buf0; A(1)->regs in flight ----
  loadA();
  convA(smem);                     // compiler waits A(0) vmcnt
  loadA();                         // A(1)
  asm volatile("s_waitcnt lgkmcnt(0)" ::: "memory");
  __builtin_amdgcn_s_barrier();
  __builtin_amdgcn_sched_barrier(0);

  for (int t = 0; t < 32; ++t) {
    stageB();                              // B(t) -> Blds (12 gl_lds)
    if (t < 31) convA(smem + ((t + 1) & 1) * 8704);  // waits A(t+1); leaves B(t) in flight
    if (t < 30) loadA();                   // A(t+2), newest, rides across barriers
    if (t < 30) asm volatile("s_waitcnt vmcnt(6) lgkmcnt(0)" ::: "memory");  // drain B(t)
    else        asm volatile("s_waitcnt vmcnt(0) lgkmcnt(0)" ::: "memory");
    __builtin_amdgcn_s_barrier();          // B(t)+A(t) LDS visible to all waves
    __builtin_amdgcn_sched_barrier(0);
    compute(smem + (t & 1) * 8704);
    __builtin_amdgcn_s_barrier();          // readers done before next overwrite
    __builtin_amdgcn_sched_barrier(0);
  }
  __syncthreads();                         // staging buffers die; Yt phase begins

  // ---- spill acc -> Yt (bf16). Yt row i <-> Y global row r0-4+i; stride 392 (4-bank shift) ----
#pragma unroll
  for (int rt = 0; rt < 5; ++rt)
#pragma unroll
    for (int ct = 0; ct < 6; ++ct)
#pragma unroll
      for (int rg = 0; rg < 4; ++rg) {
        int l = rt * 16 + quad * 4 + rg;
        int col = wave * 96 + ct * 16 + mrow;
        Yt[l * 392 + col] = f2bf_r(acc[rt][ct][rg]);
      }
  __syncthreads();

  // ---- H[p]=tanh(sum taps + cnt*b1), p in [r0-2, r0+63]; store in-place at dead tap-2 slot ----
  // H[p] slot = Yt[p-r0+2][256+c]. Self-RMW per element: race-free (blk0/blk1 never written).
  for (int idx = tid; idx < 66 * 128; idx += 256) {
    int hl = idx >> 7, c = idx & 127;
    int p = r0 - 2 + hl;
    int i = hl + 2;                                   // tap-0 Yt row
    float h = 0.f;
    if (p >= 0) {
      float s = bf2f(Yt[i * 392 + c]);
      float cnt = 1.f;
      if (p >= 1) { s += bf2f(Yt[(i - 1) * 392 + 128 + c]); cnt += 1.f; }
      if (p >= 2) { s += bf2f(Yt[(i - 2) * 392 + 256 + c]); cnt += 1.f; }
      h = tanhf(fmaf(cnt, b1[c], s));
    }
    Yt[(i - 2) * 392 + 256 + c] = f2bf_r(h);          // = Yt[hl][256+c], holds H[r0-2+hl]
  }
  __syncthreads();

  // ---- stage-2: Z rows r0+wave*16..+15; A-frag H row = Yt[wave*16+mrow+j][256+...] ----
  f32x4 acc2[8] = {};
#pragma unroll
  for (int j = 0; j < 3; ++j) {
#pragma unroll
    for (int kk = 0; kk < 4; ++kk) {
      short8 a0 = *(const short8*)&Yt[(wave * 16 + mrow + j) * 392 + 256 + kk * 32 + quad * 8];
      const unsigned short* wp = W2t + (size_t)(j * 128 + mrow) * 128 + kk * 32 + quad * 8;
#pragma unroll
      for (int ct = 0; ct < 8; ++ct)
        acc2[ct] = MFMA16(a0, *(const short8*)(wp + ct * 16 * 128), acc2[ct]);
    }
  }

  // ---- log-softmax per row (128 cols = 16 lanes x 8 ct-regs) ----
#pragma unroll
  for (int rg = 0; rg < 4; ++rg) {
    float z[8]; float m = -1e30f;
#pragma unroll
    for (int ct = 0; ct < 8; ++ct) {
      z[ct] = acc2[ct][rg] + 3.f * b2[ct * 16 + mrow];
      m = fmaxf(m, z[ct]);
    }
#pragma unroll
    for (int off = 1; off < 16; off <<= 1) m = fmaxf(m, __shfl_xor(m, off, 64));
    float s = 0.f;
#pragma unroll
    for (int ct = 0; ct < 8; ++ct) s += __expf(z[ct] - m);
#pragma unroll
    for (int off = 1; off < 16; off <<= 1) s += __shfl_xor(s, off, 64);
    float lse = m + __logf(s);
    int grow = r0 + wave * 16 + quad * 4 + rg;
    if (grow >= 2) {
      float* op = out + (size_t)grow * 128 + mrow;
#pragma unroll
      for (int ct = 0; ct < 8; ++ct) op[ct * 16] = z[ct] - lse;
    }
  }

  // ---- fallback rows 0,1 (block 0): Z0 = tanh(Y[row][0:128]+b1) @ W2[0] + b2 ----
  if (blockIdx.x == 0) {
    __syncthreads();
    int row = tid >> 7, d = tid & 127;
    zbuf[row * 128 + d] = tanhf(bf2f(Yt[(row + 4) * 392 + d]) + b1[d]);  // blk0 cols intact
    __syncthreads();
    float zv = b2[d];
    for (int c = 0; c < 128; ++c)
      zv = fmaf(zbuf[row * 128 + c], bf2f(W2t[(size_t)d * 128 + c]), zv); // W2t[0][d][c]=W2[0][c][d]
    __syncthreads();
    zbuf[row * 128 + d] = zv;
    __syncthreads();
    float m = -1e30f;
    for (int c = 0; c < 128; ++c) m = fmaxf(m, zbuf[row * 128 + c]);
    float s = 0.f;
    for (int c = 0; c < 128; ++c) s += __expf(zbuf[row * 128 + c] - m);
    out[(size_t)row * 128 + d] = zv - m - __logf(s);
  }
}

// ---------- launch ----------
extern "C" void kernel_launch(void* const* d_in, const int* in_sizes, int n_in,
                              void* d_out, int out_size, void* d_ws, size_t ws_size,
                              hipStream_t stream) {
  const float* X  = (const float*)d_in[0];   // [32768, 1, 2048]
  const float* W1 = (const float*)d_in[1];   // [3, 2048, 128]
  const float* b1 = (const float*)d_in[2];   // [1, 128]
  const float* W2 = (const float*)d_in[3];   // [3, 128, 128]
  const float* b2 = (const float*)d_in[4];   // [1, 128]
  float* out = (float*)d_out;                // [32768, 1, 128] fp32

  unsigned short* W1bt = (unsigned short*)d_ws;                    // 384*2048*2 = 1,572,864
  unsigned short* W2t  = (unsigned short*)((char*)d_ws + 1572864); // 98,304

  k_repack<<<288, 256, 0, stream>>>(W1, W2, W1bt, W2t);
  k_fused<<<512, 256, 0, stream>>>(X, W1bt, W2t, b1, b2, out);
}